// Round 5
// baseline (318.803 us; speedup 1.0000x reference)
//
#include <hip/hip_runtime.h>
#include <hip/hip_bf16.h>
#include <math.h>

#define NB 8
#define CC 512
#define HH 64
#define WW 64
#define GG 16
#define GCH 32
#define OO 32                      // 2*G offset rows
#define NGHW (NB * GG * HH * WW)   // 524288 elements per coord buffer
#define NPX  (NB * HH * WW)        // 32768 pixels
#define XROW 520                   // LDS x1 row stride in bf16 (1040 B -> MFMA reads spread banks)

// ws layout: [0, 4 MiB) px/py coords. (x1 never touches HBM.)

__device__ __forceinline__ float gelu_exact(float x) {
    return 0.5f * x * (1.0f + erff(x * 0.70710678118654752f));
}

__device__ __forceinline__ unsigned pack_bf2(float a, float b) {
    __hip_bfloat162 t = __float22bfloat162_rn(make_float2(a, b));
    return *(unsigned*)&t;
}

typedef __attribute__((ext_vector_type(8))) short bf16x8;
typedef __attribute__((ext_vector_type(4))) float f32x4;

// ============================================================================
// Fused kernel: dwconv3x3 + LayerNorm + GELU + offset-GEMM -> coords.
// Round-3 lesson: with 1024-thread blocks, occupancy quantizes in 16-wave
// steps -- alloc(56 VGPR + MFMA regs) > 64 total -> 7 waves/SIMD -> ONE
// block/CU (40%). This round: 512-thread blocks (8-wave granularity) over
// 32-px half-rows, grid (128, 8). Same proven 56-VGPR conv layout; LDS 34 KB
// -> 3-4 blocks/CU (75-100%) with ZERO spills. Block-edge halo = masked
// scalar loads of the neighbor column (L2-hot).
// ============================================================================
__global__ __launch_bounds__(512, 6)
void fused_conv_ln_gelu_off_kernel(const float* __restrict__ in_first,
                                   const float* __restrict__ dw_w,
                                   const float* __restrict__ dw_b,
                                   const float* __restrict__ ln_g,
                                   const float* __restrict__ ln_b,
                                   const float* __restrict__ off_w,
                                   const float* __restrict__ off_b,
                                   float* __restrict__ coords)
{
    const int bx   = blockIdx.x;
    const int h    = bx >> 1;
    const int w0   = (bx & 1) * 32;   // this block's 32-px half-row
    const int n    = blockIdx.y;
    const int tid  = threadIdx.x;
    const int wq   = tid & 15;        // 16 groups of 2 px
    const int cgrp = tid >> 4;        // 32 groups of 16 channels
    const int wb   = wq * 2;          // local px base (0..30)
    const int c0   = cgrp * 16;
    const int wave = tid >> 6;        // 8 waves
    const int lane = tid & 63;

    __shared__ short xbuf[32 * XROW];   // 33280 B bf16 x1 (redS aliases its head)
    __shared__ float mu_s[32];
    __shared__ float rs_s[32];
    float* redS  = (float*)xbuf;        // [8][32] partial sums (1 KB, dead before xbuf written)
    float* redS2 = (float*)xbuf + 256;  // [8][32]

    // ---------- depthwise 3x3 conv + bias (proven 56-VGPR layout) ----------
    float xv[2][16];                    // fully-unrolled static accesses only
    float sw0 = 0.f, sw1 = 0.f, sq0 = 0.f, sq1 = 0.f;

    const float* inbase = in_first + ((size_t)n * CC + c0) * HH * WW;

    #pragma unroll
    for (int i = 0; i < 16; ++i) {
        const int c = c0 + i;
        float w9[9];
        #pragma unroll
        for (int k = 0; k < 9; ++k) w9[k] = dw_w[c * 9 + k];
        const float b = dw_b[c];
        float a0 = b, a1 = b;
        #pragma unroll
        for (int r = 0; r < 3; ++r) {
            const int y = h + r - 1;
            if (y < 0 || y >= HH) continue;           // uniform across block
            const float* rowp0 = inbase + ((size_t)i * HH + y) * WW + w0;
            const float2 m = *(const float2*)(rowp0 + wb);
            float left  = __shfl_up(m.y, 1);    // lane-1 is wq-1 same cgrp (interior)
            float right = __shfl_down(m.x, 1);  // lane+1 is wq+1 same cgrp (interior)
            // block-edge halo: neighbor column from global (L2-hot), 0 at image edge
            if (wq == 0)  left  = (w0 > 0)       ? rowp0[-1] : 0.0f;
            if (wq == 15) right = (w0 + 32 < WW) ? rowp0[32] : 0.0f;
            const float k0 = w9[r * 3 + 0], k1 = w9[r * 3 + 1], k2 = w9[r * 3 + 2];
            a0 += k0 * left + k1 * m.x + k2 * m.y;
            a1 += k0 * m.x  + k1 * m.y + k2 * right;
        }
        xv[0][i] = a0; xv[1][i] = a1;
        sw0 += a0; sq0 += a0 * a0;
        sw1 += a1; sq1 += a1 * a1;
    }

    // ---------- LayerNorm stats: shfl over the wave's 4 cgrps, LDS over 8 waves ----------
    sw0 += __shfl_xor(sw0, 16); sq0 += __shfl_xor(sq0, 16);
    sw0 += __shfl_xor(sw0, 32); sq0 += __shfl_xor(sq0, 32);
    sw1 += __shfl_xor(sw1, 16); sq1 += __shfl_xor(sq1, 16);
    sw1 += __shfl_xor(sw1, 32); sq1 += __shfl_xor(sq1, 32);
    if (lane < 16) {
        redS [wave * 32 + wb + 0] = sw0;  redS2[wave * 32 + wb + 0] = sq0;
        redS [wave * 32 + wb + 1] = sw1;  redS2[wave * 32 + wb + 1] = sq1;
    }
    __syncthreads();
    if (tid < 32) {
        float s = 0.f, s2 = 0.f;
        #pragma unroll
        for (int k = 0; k < 8; ++k) {
            s  += redS [k * 32 + tid];
            s2 += redS2[k * 32 + tid];
        }
        const float mu  = s * (1.0f / 512.0f);
        const float var = s2 * (1.0f / 512.0f) - mu * mu;
        mu_s[tid] = mu;
        rs_s[tid] = rsqrtf(var + 1e-6f);
    }
    __syncthreads();   // redS reads done; xbuf (aliasing) may now be written

    // ---------- LN affine + exact GELU + bf16 pack -> LDS x1 ----------
    {
        const float mu0 = mu_s[wb + 0], rs0 = rs_s[wb + 0];
        const float mu1 = mu_s[wb + 1], rs1 = rs_s[wb + 1];
        unsigned pk0[8], pk1[8];
        #pragma unroll
        for (int t = 0; t < 8; ++t) {
            const int c = c0 + 2 * t;
            const float lgA = ln_g[c],     lbA = ln_b[c];
            const float lgB = ln_g[c + 1], lbB = ln_b[c + 1];
            const float v0a = (xv[0][2 * t]     - mu0) * rs0 * lgA + lbA;
            const float v0b = (xv[0][2 * t + 1] - mu0) * rs0 * lgB + lbB;
            const float v1a = (xv[1][2 * t]     - mu1) * rs1 * lgA + lbA;
            const float v1b = (xv[1][2 * t + 1] - mu1) * rs1 * lgB + lbB;
            pk0[t] = pack_bf2(gelu_exact(v0a), gelu_exact(v0b));
            pk1[t] = pack_bf2(gelu_exact(v1a), gelu_exact(v1b));
        }
        short* p0 = xbuf + (size_t)(wb + 0) * XROW + c0;
        short* p1 = xbuf + (size_t)(wb + 1) * XROW + c0;
        *(uint4*)(p0)     = make_uint4(pk0[0], pk0[1], pk0[2], pk0[3]);
        *(uint4*)(p0 + 8) = make_uint4(pk0[4], pk0[5], pk0[6], pk0[7]);
        *(uint4*)(p1)     = make_uint4(pk1[0], pk1[1], pk1[2], pk1[3]);
        *(uint4*)(p1 + 8) = make_uint4(pk1[4], pk1[5], pk1[6], pk1[7]);
    }
    __syncthreads();

    // ---------- offset GEMM: waves 0-3, each one 16(px) x 16(o) tile, K=512 ----------
    // C/D layout (verified m89/m91): col = lane&15, row = (lane>>4)*4 + reg.
    if (wave < 4) {
        const int ml   = lane & 15;
        const int quad = lane >> 4;
        const int pxT  = wave >> 1;
        const int oT   = wave & 1;

        const short* arow = xbuf + (size_t)(pxT * 16 + ml) * XROW + quad * 8;
        const float* brow = off_w + (size_t)(oT * 16 + ml) * CC + quad * 8;

        f32x4 acc = {0.f, 0.f, 0.f, 0.f};
        for (int k = 0; k < CC; k += 32) {
            const bf16x8 af = *(const bf16x8*)(arow + k);
            const float4 p = *(const float4*)(brow + k);
            const float4 q = *(const float4*)(brow + k + 4);
            union { bf16x8 v; unsigned u[4]; } bb;
            bb.u[0] = pack_bf2(p.x, p.y); bb.u[1] = pack_bf2(p.z, p.w);
            bb.u[2] = pack_bf2(q.x, q.y); bb.u[3] = pack_bf2(q.z, q.w);
            acc = __builtin_amdgcn_mfma_f32_16x16x32_bf16(af, bb.v, acc, 0, 0, 0);
        }

        const int   o   = oT * 16 + ml;
        const float ob  = off_b[o];
        const int   par = o & 1;            // even o -> x-offset, odd -> y-offset
        const int   g   = o >> 1;
        #pragma unroll
        for (int r = 0; r < 4; ++r) {
            const int w = w0 + pxT * 16 + quad * 4 + r;
            const float base = par ? (float)h : (float)w;
            coords[(size_t)par * NGHW + (((size_t)n * GG + g) * HH + h) * WW + w]
                = base + acc[r] + ob;
        }
    }
}

// ============================================================================
// Kernel 2: bilinear gather (unchanged from round 3 -- three structural
// variants measured identical; not the lever). Nontemporal out stores.
// ============================================================================
__global__ __launch_bounds__(256)
void sample_kernel(const float* __restrict__ in_last,
                   const float* __restrict__ coord_ws,
                   float* __restrict__ out)
{
    // bijective XCD swizzle: 8192 % 8 == 0; nb ordering is (g, n, h) with h fastest
    const int bid = blockIdx.x;
    const int nb  = (bid & 7) * 1024 + (bid >> 3);
    const int h   = nb & 63;
    const int n   = (nb >> 6) & 7;
    const int g   = nb >> 9;
    const int tid = threadIdx.x;

    __shared__ float pxs[64];
    __shared__ float pys[64];
    __shared__ float smem[64 * 33];

    if (tid < 128) {
        const int w = tid & 63;
        const size_t cidx = (((size_t)n * GG + g) * HH + h) * WW + w;
        if (tid < 64) pxs[w] = coord_ws[cidx];
        else          pys[w] = coord_ws[cidx + NGHW];
    }
    __syncthreads();

    const int c4    = tid & 7;      // 8 groups of 4 channels
    const int wslot = tid >> 3;     // 32 px slots (x2 passes)
    const float* base = in_last + (size_t)n * HH * WW * CC + g * GCH + c4 * 4;

    int   off[8];
    float wt [8];
    #pragma unroll
    for (int p = 0; p < 2; ++p) {
        const int w = wslot + p * 32;
        const float px = pxs[w];
        const float py = pys[w];
        const float x0f = floorf(px), y0f = floorf(py);
        const float fx = px - x0f, fy = py - y0f;
        const int x0 = (int)x0f, y0 = (int)y0f;
        #pragma unroll
        for (int t = 0; t < 4; ++t) {
            const int xi = x0 + (t & 1);
            const int yi = y0 + (t >> 1);
            const int xc = min(max(xi, 0), WW - 1);
            const int yc = min(max(yi, 0), HH - 1);
            const float valid = (xi >= 0 && xi < WW && yi >= 0 && yi < HH) ? 1.0f : 0.0f;
            wt [p * 4 + t] = ((t & 1) ? fx : 1.0f - fx) * ((t >> 1) ? fy : 1.0f - fy) * valid;
            off[p * 4 + t] = (yc * WW + xc) * CC;
        }
    }
    // all 8 independent loads in flight before any consume
    float4 v[8];
    #pragma unroll
    for (int i = 0; i < 8; ++i) v[i] = *(const float4*)(base + off[i]);

    float4 a0 = make_float4(0.f, 0.f, 0.f, 0.f);
    float4 a1 = make_float4(0.f, 0.f, 0.f, 0.f);
    #pragma unroll
    for (int t = 0; t < 4; ++t) {
        a0.x += wt[t] * v[t].x;     a0.y += wt[t] * v[t].y;
        a0.z += wt[t] * v[t].z;     a0.w += wt[t] * v[t].w;
        a1.x += wt[4 + t] * v[4 + t].x; a1.y += wt[4 + t] * v[4 + t].y;
        a1.z += wt[4 + t] * v[4 + t].z; a1.w += wt[4 + t] * v[4 + t].w;
    }
    {
        float* sp0 = smem + wslot * 33 + c4 * 4;
        float* sp1 = smem + (wslot + 32) * 33 + c4 * 4;
        sp0[0] = a0.x; sp0[1] = a0.y; sp0[2] = a0.z; sp0[3] = a0.w;
        sp1[0] = a1.x; sp1[1] = a1.y; sp1[2] = a1.z; sp1[3] = a1.w;
    }
    __syncthreads();

    // transpose out of LDS, float4 along w, nontemporal (write-once stream)
    const int c  = tid >> 4;            // 0..15 (x2 passes)
    const int w4 = (tid & 15) * 4;
    #pragma unroll
    for (int p = 0; p < 2; ++p) {
        const int cc = c + p * 16;
        f32x4 o;
        o.x = smem[(w4 + 0) * 33 + cc];
        o.y = smem[(w4 + 1) * 33 + cc];
        o.z = smem[(w4 + 2) * 33 + cc];
        o.w = smem[(w4 + 3) * 33 + cc];
        __builtin_nontemporal_store(
            o, (f32x4*)(out + (((size_t)n * CC + g * GCH + cc) * HH + h) * WW + w4));
    }
}

extern "C" void kernel_launch(void* const* d_in, const int* in_sizes, int n_in,
                              void* d_out, int out_size, void* d_ws, size_t ws_size,
                              hipStream_t stream) {
    const float* in_first = (const float*)d_in[0];
    const float* in_last  = (const float*)d_in[1];
    const float* dw_w     = (const float*)d_in[2];
    const float* dw_b     = (const float*)d_in[3];
    const float* ln_g     = (const float*)d_in[4];
    const float* ln_b     = (const float*)d_in[5];
    const float* off_w    = (const float*)d_in[6];
    const float* off_b    = (const float*)d_in[7];
    float* out = (float*)d_out;

    float* coord_ws = (float*)d_ws;     // 4 MiB

    dim3 gridA(HH * 2, NB);
    fused_conv_ln_gelu_off_kernel<<<gridA, 512, 0, stream>>>(
        in_first, dw_w, dw_b, ln_g, ln_b, off_w, off_b, coord_ws);

    sample_kernel<<<HH * NB * GG, 256, 0, stream>>>(in_last, coord_ws, out);
}

// Round 6
// 243.038 us; speedup vs baseline: 1.3117x; 1.3117x over previous
//
#include <hip/hip_runtime.h>
#include <hip/hip_bf16.h>
#include <math.h>

#define NB 8
#define CC 512
#define HH 64
#define WW 64
#define GG 16
#define GCH 32
#define OO 32                      // 2*G offset rows
#define NGHW (NB * GG * HH * WW)   // 524288 elements per coord buffer
#define NPX  (NB * HH * WW)        // 32768 pixels
#define XROW 520                   // LDS x1 row stride in bf16 (1040 B -> balanced bank groups)

// ws layout: [0, 4 MiB) px/py coords. (x1 never touches HBM.)

__device__ __forceinline__ float gelu_exact(float x) {
    return 0.5f * x * (1.0f + erff(x * 0.70710678118654752f));
}

__device__ __forceinline__ unsigned pack_bf2(float a, float b) {
    __hip_bfloat162 t = __float22bfloat162_rn(make_float2(a, b));
    return *(unsigned*)&t;
}

typedef __attribute__((ext_vector_type(8))) short bf16x8;
typedef __attribute__((ext_vector_type(4))) float f32x4;

// ============================================================================
// Fused kernel: dwconv3x3 + LayerNorm + GELU + offset-GEMM -> coords.
// Round-5 lesson: __launch_bounds__ min-waves coerces VGPR down -> spills
// (r2: 32/170MB, r5: 40/120MB). This round: NO coercion -- (512,4) is a pure
// spill-guard (cap 128). Layout = 4px x 8ch (float4 loads, the round-2
// bytes-in-flight winner) on 32-px half-rows, 512-thread blocks:
//   xv[4][8]=32 regs -> expect ~60-72 VGPR -> 7-8 waves/SIMD by HW arithmetic
//   LDS 34 KB -> 4 blocks/CU; grid 1024 -> 4 blocks/CU available.
// XCD swizzle: each XCD owns one image n (128 half-row blocks) -> vertical
// (h+-1) and horizontal (halo column) neighbors share an XCD L2.
// ============================================================================
__global__ __launch_bounds__(512, 4)
void fused_conv_ln_gelu_off_kernel(const float* __restrict__ in_first,
                                   const float* __restrict__ dw_w,
                                   const float* __restrict__ dw_b,
                                   const float* __restrict__ ln_g,
                                   const float* __restrict__ ln_b,
                                   const float* __restrict__ off_w,
                                   const float* __restrict__ off_b,
                                   float* __restrict__ coords)
{
    // XCD swizzle: 1024 blocks, 8 XCDs, bid%8 = XCD -> nb = xcd*128 + bid/8.
    // XCD k then runs exactly image n=k: all h/halo neighbors on one L2.
    const int bid = blockIdx.x;
    const int nb  = (bid & 7) * 128 + (bid >> 3);
    const int n   = nb >> 7;
    const int h   = (nb & 127) >> 1;
    const int w0  = (nb & 1) * 32;    // this block's 32-px half-row

    const int tid  = threadIdx.x;
    const int wq   = tid & 7;         // 8 groups of 4 px
    const int cgrp = tid >> 3;        // 64 groups of 8 channels
    const int wb   = wq * 4;          // local px base (0..28)
    const int c0   = cgrp * 8;
    const int wave = tid >> 6;        // 8 waves
    const int lane = tid & 63;

    __shared__ short xbuf[32 * XROW];   // 33280 B bf16 x1 (redS aliases its head)
    __shared__ float mu_s[32];
    __shared__ float rs_s[32];
    float* redS  = (float*)xbuf;        // [8][32] partial sums (1 KB, dead before xbuf written)
    float* redS2 = (float*)xbuf + 256;  // [8][32]

    // ---------- depthwise 3x3 conv + bias (float4 loads, 32-reg accumulator) ----------
    float xv[4][8];                     // fully-unrolled static accesses only
    float sw[4] = {0.f, 0.f, 0.f, 0.f};
    float sq[4] = {0.f, 0.f, 0.f, 0.f};

    const float* inbase = in_first + ((size_t)n * CC + c0) * HH * WW;

    #pragma unroll
    for (int i = 0; i < 8; ++i) {
        const int c = c0 + i;
        float w9[9];
        #pragma unroll
        for (int k = 0; k < 9; ++k) w9[k] = dw_w[c * 9 + k];
        const float b = dw_b[c];
        float a0 = b, a1 = b, a2 = b, a3 = b;
        #pragma unroll
        for (int r = 0; r < 3; ++r) {
            const int y = h + r - 1;
            if (y < 0 || y >= HH) continue;           // uniform across block
            const float* rowp0 = inbase + ((size_t)i * HH + y) * WW + w0;
            const float4 m = *(const float4*)(rowp0 + wb);
            float left  = __shfl_up(m.w, 1);    // lane-1 is wq-1 same cgrp (interior)
            float right = __shfl_down(m.x, 1);  // lane+1 is wq+1 same cgrp (interior)
            // block-edge halo: neighbor column from global (same-XCD L2), 0 at image edge
            if (wq == 0) left  = (w0 > 0)       ? rowp0[-1] : 0.0f;
            if (wq == 7) right = (w0 + 32 < WW) ? rowp0[32] : 0.0f;
            const float k0 = w9[r * 3 + 0], k1 = w9[r * 3 + 1], k2 = w9[r * 3 + 2];
            a0 += k0 * left + k1 * m.x + k2 * m.y;
            a1 += k0 * m.x  + k1 * m.y + k2 * m.z;
            a2 += k0 * m.y  + k1 * m.z + k2 * m.w;
            a3 += k0 * m.z  + k1 * m.w + k2 * right;
        }
        xv[0][i] = a0; xv[1][i] = a1; xv[2][i] = a2; xv[3][i] = a3;
        sw[0] += a0; sq[0] += a0 * a0;
        sw[1] += a1; sq[1] += a1 * a1;
        sw[2] += a2; sq[2] += a2 * a2;
        sw[3] += a3; sq[3] += a3 * a3;
    }

    // ---------- LayerNorm stats: shfl over the wave's 8 cgrp slots (lane bits 3-5) ----------
    #pragma unroll
    for (int j = 0; j < 4; ++j) {
        sw[j] += __shfl_xor(sw[j], 8);  sq[j] += __shfl_xor(sq[j], 8);
        sw[j] += __shfl_xor(sw[j], 16); sq[j] += __shfl_xor(sq[j], 16);
        sw[j] += __shfl_xor(sw[j], 32); sq[j] += __shfl_xor(sq[j], 32);
    }
    if (lane < 8) {
        #pragma unroll
        for (int j = 0; j < 4; ++j) {
            redS [wave * 32 + wb + j] = sw[j];
            redS2[wave * 32 + wb + j] = sq[j];
        }
    }
    __syncthreads();
    if (tid < 32) {
        float s = 0.f, s2 = 0.f;
        #pragma unroll
        for (int k = 0; k < 8; ++k) {
            s  += redS [k * 32 + tid];
            s2 += redS2[k * 32 + tid];
        }
        const float mu  = s * (1.0f / 512.0f);
        const float var = s2 * (1.0f / 512.0f) - mu * mu;
        mu_s[tid] = mu;
        rs_s[tid] = rsqrtf(var + 1e-6f);
    }
    __syncthreads();   // redS reads done; xbuf (aliasing) may now be written

    // ---------- LN affine + exact GELU + bf16 pack -> LDS x1 ----------
    {
        float mu_[4], rs_[4];
        #pragma unroll
        for (int j = 0; j < 4; ++j) { mu_[j] = mu_s[wb + j]; rs_[j] = rs_s[wb + j]; }
        unsigned pk[4][4];
        #pragma unroll
        for (int t = 0; t < 4; ++t) {           // channel pairs
            const int c = c0 + 2 * t;
            const float lgA = ln_g[c],     lbA = ln_b[c];
            const float lgB = ln_g[c + 1], lbB = ln_b[c + 1];
            #pragma unroll
            for (int j = 0; j < 4; ++j) {
                const float va = (xv[j][2 * t]     - mu_[j]) * rs_[j] * lgA + lbA;
                const float vb = (xv[j][2 * t + 1] - mu_[j]) * rs_[j] * lgB + lbB;
                pk[j][t] = pack_bf2(gelu_exact(va), gelu_exact(vb));
            }
        }
        #pragma unroll
        for (int j = 0; j < 4; ++j) {
            *(uint4*)(xbuf + (size_t)(wb + j) * XROW + c0)
                = make_uint4(pk[j][0], pk[j][1], pk[j][2], pk[j][3]);
        }
    }
    __syncthreads();

    // ---------- offset GEMM: waves 0-3, each one 16(px) x 16(o) tile, K=512 ----------
    // C/D layout (verified m89/m91): col = lane&15, row = (lane>>4)*4 + reg.
    if (wave < 4) {
        const int ml   = lane & 15;
        const int quad = lane >> 4;
        const int pxT  = wave >> 1;
        const int oT   = wave & 1;

        const short* arow = xbuf + (size_t)(pxT * 16 + ml) * XROW + quad * 8;
        const float* brow = off_w + (size_t)(oT * 16 + ml) * CC + quad * 8;

        f32x4 acc = {0.f, 0.f, 0.f, 0.f};
        for (int k = 0; k < CC; k += 32) {
            const bf16x8 af = *(const bf16x8*)(arow + k);
            const float4 p = *(const float4*)(brow + k);
            const float4 q = *(const float4*)(brow + k + 4);
            union { bf16x8 v; unsigned u[4]; } bb;
            bb.u[0] = pack_bf2(p.x, p.y); bb.u[1] = pack_bf2(p.z, p.w);
            bb.u[2] = pack_bf2(q.x, q.y); bb.u[3] = pack_bf2(q.z, q.w);
            acc = __builtin_amdgcn_mfma_f32_16x16x32_bf16(af, bb.v, acc, 0, 0, 0);
        }

        const int   o   = oT * 16 + ml;
        const float ob  = off_b[o];
        const int   par = o & 1;            // even o -> x-offset, odd -> y-offset
        const int   g   = o >> 1;
        #pragma unroll
        for (int r = 0; r < 4; ++r) {
            const int w = w0 + pxT * 16 + quad * 4 + r;
            const float base = par ? (float)h : (float)w;
            coords[(size_t)par * NGHW + (((size_t)n * GG + g) * HH + h) * WW + w]
                = base + acc[r] + ob;
        }
    }
}

// ============================================================================
// Kernel 2: bilinear gather (structure frozen; measured insensitive to
// variants). Nontemporal out stores; XCD swizzle.
// ============================================================================
__global__ __launch_bounds__(256)
void sample_kernel(const float* __restrict__ in_last,
                   const float* __restrict__ coord_ws,
                   float* __restrict__ out)
{
    // bijective XCD swizzle: 8192 % 8 == 0; nb ordering is (g, n, h) with h fastest
    const int bid = blockIdx.x;
    const int nb  = (bid & 7) * 1024 + (bid >> 3);
    const int h   = nb & 63;
    const int n   = (nb >> 6) & 7;
    const int g   = nb >> 9;
    const int tid = threadIdx.x;

    __shared__ float pxs[64];
    __shared__ float pys[64];
    __shared__ float smem[64 * 33];

    if (tid < 128) {
        const int w = tid & 63;
        const size_t cidx = (((size_t)n * GG + g) * HH + h) * WW + w;
        if (tid < 64) pxs[w] = coord_ws[cidx];
        else          pys[w] = coord_ws[cidx + NGHW];
    }
    __syncthreads();

    const int c4    = tid & 7;      // 8 groups of 4 channels
    const int wslot = tid >> 3;     // 32 px slots (x2 passes)
    const float* base = in_last + (size_t)n * HH * WW * CC + g * GCH + c4 * 4;

    int   off[8];
    float wt [8];
    #pragma unroll
    for (int p = 0; p < 2; ++p) {
        const int w = wslot + p * 32;
        const float px = pxs[w];
        const float py = pys[w];
        const float x0f = floorf(px), y0f = floorf(py);
        const float fx = px - x0f, fy = py - y0f;
        const int x0 = (int)x0f, y0 = (int)y0f;
        #pragma unroll
        for (int t = 0; t < 4; ++t) {
            const int xi = x0 + (t & 1);
            const int yi = y0 + (t >> 1);
            const int xc = min(max(xi, 0), WW - 1);
            const int yc = min(max(yi, 0), HH - 1);
            const float valid = (xi >= 0 && xi < WW && yi >= 0 && yi < HH) ? 1.0f : 0.0f;
            wt [p * 4 + t] = ((t & 1) ? fx : 1.0f - fx) * ((t >> 1) ? fy : 1.0f - fy) * valid;
            off[p * 4 + t] = (yc * WW + xc) * CC;
        }
    }
    // all 8 independent loads in flight before any consume
    float4 v[8];
    #pragma unroll
    for (int i = 0; i < 8; ++i) v[i] = *(const float4*)(base + off[i]);

    float4 a0 = make_float4(0.f, 0.f, 0.f, 0.f);
    float4 a1 = make_float4(0.f, 0.f, 0.f, 0.f);
    #pragma unroll
    for (int t = 0; t < 4; ++t) {
        a0.x += wt[t] * v[t].x;     a0.y += wt[t] * v[t].y;
        a0.z += wt[t] * v[t].z;     a0.w += wt[t] * v[t].w;
        a1.x += wt[4 + t] * v[4 + t].x; a1.y += wt[4 + t] * v[4 + t].y;
        a1.z += wt[4 + t] * v[4 + t].z; a1.w += wt[4 + t] * v[4 + t].w;
    }
    {
        float* sp0 = smem + wslot * 33 + c4 * 4;
        float* sp1 = smem + (wslot + 32) * 33 + c4 * 4;
        sp0[0] = a0.x; sp0[1] = a0.y; sp0[2] = a0.z; sp0[3] = a0.w;
        sp1[0] = a1.x; sp1[1] = a1.y; sp1[2] = a1.z; sp1[3] = a1.w;
    }
    __syncthreads();

    // transpose out of LDS, float4 along w, nontemporal (write-once stream)
    const int c  = tid >> 4;            // 0..15 (x2 passes)
    const int w4 = (tid & 15) * 4;
    #pragma unroll
    for (int p = 0; p < 2; ++p) {
        const int cc = c + p * 16;
        f32x4 o;
        o.x = smem[(w4 + 0) * 33 + cc];
        o.y = smem[(w4 + 1) * 33 + cc];
        o.z = smem[(w4 + 2) * 33 + cc];
        o.w = smem[(w4 + 3) * 33 + cc];
        __builtin_nontemporal_store(
            o, (f32x4*)(out + (((size_t)n * CC + g * GCH + cc) * HH + h) * WW + w4));
    }
}

extern "C" void kernel_launch(void* const* d_in, const int* in_sizes, int n_in,
                              void* d_out, int out_size, void* d_ws, size_t ws_size,
                              hipStream_t stream) {
    const float* in_first = (const float*)d_in[0];
    const float* in_last  = (const float*)d_in[1];
    const float* dw_w     = (const float*)d_in[2];
    const float* dw_b     = (const float*)d_in[3];
    const float* ln_g     = (const float*)d_in[4];
    const float* ln_b     = (const float*)d_in[5];
    const float* off_w    = (const float*)d_in[6];
    const float* off_b    = (const float*)d_in[7];
    float* out = (float*)d_out;

    float* coord_ws = (float*)d_ws;     // 4 MiB

    fused_conv_ln_gelu_off_kernel<<<HH * 2 * NB, 512, 0, stream>>>(
        in_first, dw_w, dw_b, ln_g, ln_b, off_w, off_b, coord_ws);

    sample_kernel<<<HH * NB * GG, 256, 0, stream>>>(in_last, coord_ws, out);
}

// Round 7
// 236.929 us; speedup vs baseline: 1.3456x; 1.0258x over previous
//
#include <hip/hip_runtime.h>
#include <hip/hip_bf16.h>
#include <math.h>

#define NB 8
#define CC 512
#define HH 64
#define WW 64
#define GG 16
#define GCH 32
#define OO 32                      // 2*G offset rows
#define NGHW (NB * GG * HH * WW)   // 524288 elements per coord buffer
#define NPX  (NB * HH * WW)        // 32768 pixels
#define XROW 520                   // LDS x1 row stride in bf16 (1040 B -> balanced bank groups)

// ws layout: [0, 4 MiB) px/py coords. (x1 never touches HBM.)

__device__ __forceinline__ float gelu_exact(float x) {
    return 0.5f * x * (1.0f + erff(x * 0.70710678118654752f));
}

__device__ __forceinline__ unsigned pack_bf2(float a, float b) {
    __hip_bfloat162 t = __float22bfloat162_rn(make_float2(a, b));
    return *(unsigned*)&t;
}

typedef __attribute__((ext_vector_type(8))) short bf16x8;
typedef __attribute__((ext_vector_type(4))) float f32x4;

// ============================================================================
// Fused kernel: dwconv3x3 + LayerNorm + GELU + offset-GEMM -> coords.
// Round-6 lesson: spill-free + 33 MB fetch ran the SAME 85 us as the spilling
// round-2 version -> traffic was never the cost; the latency structure is.
// The invariant: ~96 scattered 4-B parameter loads (dw_w/dw_b/ln_g/ln_b) per
// thread INSIDE the conv dependency chain, unhideable at 56 VGPR. This round:
// stage all params in LDS once per block (coalesced), conv reads them via
// broadcast ds_read (<=2-way alias = free).
// LDS aliasing (audited): bytes 0-2047 of xbuf = redS/redS2 (conv phase);
// bytes 2048-22527 = dw_w+dw_b (dead after conv, overwritten by xbuf rows in
// the LN phase); ln_g/ln_b live separately (read while xbuf is written).
// Total 37632 B <= 40960 -> 4 blocks/CU retained.
// ============================================================================
__global__ __launch_bounds__(512, 4)
void fused_conv_ln_gelu_off_kernel(const float* __restrict__ in_first,
                                   const float* __restrict__ dw_w,
                                   const float* __restrict__ dw_b,
                                   const float* __restrict__ ln_g,
                                   const float* __restrict__ ln_b,
                                   const float* __restrict__ off_w,
                                   const float* __restrict__ off_b,
                                   float* __restrict__ coords)
{
    // XCD swizzle: 1024 blocks, 8 XCDs, bid%8 = XCD -> nb = xcd*128 + bid/8.
    // XCD k then runs exactly image n=k: all h/halo neighbors on one L2.
    const int bid = blockIdx.x;
    const int nb  = (bid & 7) * 128 + (bid >> 3);
    const int n   = nb >> 7;
    const int h   = (nb & 127) >> 1;
    const int w0  = (nb & 1) * 32;    // this block's 32-px half-row

    const int tid  = threadIdx.x;
    const int wq   = tid & 7;         // 8 groups of 4 px
    const int cgrp = tid >> 3;        // 64 groups of 8 channels
    const int wb   = wq * 4;          // local px base (0..28)
    const int c0   = cgrp * 8;
    const int wave = tid >> 6;        // 8 waves
    const int lane = tid & 63;

    __shared__ short xbuf[32 * XROW];   // 33280 B bf16 x1 (aliased: redS + conv params)
    __shared__ float mu_s[32];
    __shared__ float rs_s[32];
    __shared__ float lng_s[CC];         // ln params: separate (read while xbuf written)
    __shared__ float lnb_s[CC];
    float* redS  = (float*)xbuf;        // [8][32] partial sums   bytes 0..1023
    float* redS2 = (float*)xbuf + 256;  // [8][32]                bytes 1024..2047
    float* w_s   = (float*)xbuf + 512;  // dw_w [512*9]           bytes 2048..20479
    float* b_s   = w_s + CC * 9;        // dw_b [512]             bytes 20480..22527

    // ---------- phase 0: stage all parameters in LDS (coalesced) ----------
    #pragma unroll
    for (int it = 0; it < 9; ++it) w_s[it * 512 + tid] = dw_w[it * 512 + tid];
    b_s  [tid] = dw_b[tid];
    lng_s[tid] = ln_g[tid];
    lnb_s[tid] = ln_b[tid];
    __syncthreads();

    // ---------- depthwise 3x3 conv + bias (float4 loads; weights from LDS) ----------
    float xv[4][8];                     // fully-unrolled static accesses only
    float sw[4] = {0.f, 0.f, 0.f, 0.f};
    float sq[4] = {0.f, 0.f, 0.f, 0.f};

    const float* inbase = in_first + ((size_t)n * CC + c0) * HH * WW;

    #pragma unroll
    for (int i = 0; i < 8; ++i) {
        const int c = c0 + i;
        const float* wrow = w_s + c * 9;    // broadcast across the 8 lanes of this cgrp
        float w9[9];
        #pragma unroll
        for (int k = 0; k < 9; ++k) w9[k] = wrow[k];
        const float b = b_s[c];
        float a0 = b, a1 = b, a2 = b, a3 = b;
        #pragma unroll
        for (int r = 0; r < 3; ++r) {
            const int y = h + r - 1;
            if (y < 0 || y >= HH) continue;           // uniform across block
            const float* rowp0 = inbase + ((size_t)i * HH + y) * WW + w0;
            const float4 m = *(const float4*)(rowp0 + wb);
            float left  = __shfl_up(m.w, 1);    // lane-1 is wq-1 same cgrp (interior)
            float right = __shfl_down(m.x, 1);  // lane+1 is wq+1 same cgrp (interior)
            // block-edge halo: neighbor column from global (same-XCD L2), 0 at image edge
            if (wq == 0) left  = (w0 > 0)       ? rowp0[-1] : 0.0f;
            if (wq == 7) right = (w0 + 32 < WW) ? rowp0[32] : 0.0f;
            const float k0 = w9[r * 3 + 0], k1 = w9[r * 3 + 1], k2 = w9[r * 3 + 2];
            a0 += k0 * left + k1 * m.x + k2 * m.y;
            a1 += k0 * m.x  + k1 * m.y + k2 * m.z;
            a2 += k0 * m.y  + k1 * m.z + k2 * m.w;
            a3 += k0 * m.z  + k1 * m.w + k2 * right;
        }
        xv[0][i] = a0; xv[1][i] = a1; xv[2][i] = a2; xv[3][i] = a3;
        sw[0] += a0; sq[0] += a0 * a0;
        sw[1] += a1; sq[1] += a1 * a1;
        sw[2] += a2; sq[2] += a2 * a2;
        sw[3] += a3; sq[3] += a3 * a3;
    }

    // ---------- LayerNorm stats: shfl over the wave's 8 cgrp slots (lane bits 3-5) ----------
    #pragma unroll
    for (int j = 0; j < 4; ++j) {
        sw[j] += __shfl_xor(sw[j], 8);  sq[j] += __shfl_xor(sq[j], 8);
        sw[j] += __shfl_xor(sw[j], 16); sq[j] += __shfl_xor(sq[j], 16);
        sw[j] += __shfl_xor(sw[j], 32); sq[j] += __shfl_xor(sq[j], 32);
    }
    if (lane < 8) {
        #pragma unroll
        for (int j = 0; j < 4; ++j) {
            redS [wave * 32 + wb + j] = sw[j];      // bytes 0..2047: disjoint from w_s
            redS2[wave * 32 + wb + j] = sq[j];
        }
    }
    __syncthreads();
    if (tid < 32) {
        float s = 0.f, s2 = 0.f;
        #pragma unroll
        for (int k = 0; k < 8; ++k) {
            s  += redS [k * 32 + tid];
            s2 += redS2[k * 32 + tid];
        }
        const float mu  = s * (1.0f / 512.0f);
        const float var = s2 * (1.0f / 512.0f) - mu * mu;
        mu_s[tid] = mu;
        rs_s[tid] = rsqrtf(var + 1e-6f);
    }
    __syncthreads();   // redS reads done; xbuf (incl. dead w_s region) may now be written

    // ---------- LN affine + exact GELU + bf16 pack -> LDS x1 ----------
    {
        float mu_[4], rs_[4];
        #pragma unroll
        for (int j = 0; j < 4; ++j) { mu_[j] = mu_s[wb + j]; rs_[j] = rs_s[wb + j]; }
        unsigned pk[4][4];
        #pragma unroll
        for (int t = 0; t < 4; ++t) {           // channel pairs
            const int c = c0 + 2 * t;
            const float lgA = lng_s[c],     lbA = lnb_s[c];
            const float lgB = lng_s[c + 1], lbB = lnb_s[c + 1];
            #pragma unroll
            for (int j = 0; j < 4; ++j) {
                const float va = (xv[j][2 * t]     - mu_[j]) * rs_[j] * lgA + lbA;
                const float vb = (xv[j][2 * t + 1] - mu_[j]) * rs_[j] * lgB + lbB;
                pk[j][t] = pack_bf2(gelu_exact(va), gelu_exact(vb));
            }
        }
        #pragma unroll
        for (int j = 0; j < 4; ++j) {
            *(uint4*)(xbuf + (size_t)(wb + j) * XROW + c0)
                = make_uint4(pk[j][0], pk[j][1], pk[j][2], pk[j][3]);
        }
    }
    __syncthreads();

    // ---------- offset GEMM: waves 0-3, each one 16(px) x 16(o) tile, K=512 ----------
    // C/D layout (verified m89/m91): col = lane&15, row = (lane>>4)*4 + reg.
    if (wave < 4) {
        const int ml   = lane & 15;
        const int quad = lane >> 4;
        const int pxT  = wave >> 1;
        const int oT   = wave & 1;

        const short* arow = xbuf + (size_t)(pxT * 16 + ml) * XROW + quad * 8;
        const float* brow = off_w + (size_t)(oT * 16 + ml) * CC + quad * 8;

        f32x4 acc = {0.f, 0.f, 0.f, 0.f};
        for (int k = 0; k < CC; k += 32) {
            const bf16x8 af = *(const bf16x8*)(arow + k);
            const float4 p = *(const float4*)(brow + k);
            const float4 q = *(const float4*)(brow + k + 4);
            union { bf16x8 v; unsigned u[4]; } bb;
            bb.u[0] = pack_bf2(p.x, p.y); bb.u[1] = pack_bf2(p.z, p.w);
            bb.u[2] = pack_bf2(q.x, q.y); bb.u[3] = pack_bf2(q.z, q.w);
            acc = __builtin_amdgcn_mfma_f32_16x16x32_bf16(af, bb.v, acc, 0, 0, 0);
        }

        const int   o   = oT * 16 + ml;
        const float ob  = off_b[o];
        const int   par = o & 1;            // even o -> x-offset, odd -> y-offset
        const int   g   = o >> 1;
        #pragma unroll
        for (int r = 0; r < 4; ++r) {
            const int w = w0 + pxT * 16 + quad * 4 + r;
            const float base = par ? (float)h : (float)w;
            coords[(size_t)par * NGHW + (((size_t)n * GG + g) * HH + h) * WW + w]
                = base + acc[r] + ob;
        }
    }
}

// ============================================================================
// Kernel 2: bilinear gather (structure frozen; measured insensitive to
// variants). Nontemporal out stores; XCD swizzle.
// ============================================================================
__global__ __launch_bounds__(256)
void sample_kernel(const float* __restrict__ in_last,
                   const float* __restrict__ coord_ws,
                   float* __restrict__ out)
{
    // bijective XCD swizzle: 8192 % 8 == 0; nb ordering is (g, n, h) with h fastest
    const int bid = blockIdx.x;
    const int nb  = (bid & 7) * 1024 + (bid >> 3);
    const int h   = nb & 63;
    const int n   = (nb >> 6) & 7;
    const int g   = nb >> 9;
    const int tid = threadIdx.x;

    __shared__ float pxs[64];
    __shared__ float pys[64];
    __shared__ float smem[64 * 33];

    if (tid < 128) {
        const int w = tid & 63;
        const size_t cidx = (((size_t)n * GG + g) * HH + h) * WW + w;
        if (tid < 64) pxs[w] = coord_ws[cidx];
        else          pys[w] = coord_ws[cidx + NGHW];
    }
    __syncthreads();

    const int c4    = tid & 7;      // 8 groups of 4 channels
    const int wslot = tid >> 3;     // 32 px slots (x2 passes)
    const float* base = in_last + (size_t)n * HH * WW * CC + g * GCH + c4 * 4;

    int   off[8];
    float wt [8];
    #pragma unroll
    for (int p = 0; p < 2; ++p) {
        const int w = wslot + p * 32;
        const float px = pxs[w];
        const float py = pys[w];
        const float x0f = floorf(px), y0f = floorf(py);
        const float fx = px - x0f, fy = py - y0f;
        const int x0 = (int)x0f, y0 = (int)y0f;
        #pragma unroll
        for (int t = 0; t < 4; ++t) {
            const int xi = x0 + (t & 1);
            const int yi = y0 + (t >> 1);
            const int xc = min(max(xi, 0), WW - 1);
            const int yc = min(max(yi, 0), HH - 1);
            const float valid = (xi >= 0 && xi < WW && yi >= 0 && yi < HH) ? 1.0f : 0.0f;
            wt [p * 4 + t] = ((t & 1) ? fx : 1.0f - fx) * ((t >> 1) ? fy : 1.0f - fy) * valid;
            off[p * 4 + t] = (yc * WW + xc) * CC;
        }
    }
    // all 8 independent loads in flight before any consume
    float4 v[8];
    #pragma unroll
    for (int i = 0; i < 8; ++i) v[i] = *(const float4*)(base + off[i]);

    float4 a0 = make_float4(0.f, 0.f, 0.f, 0.f);
    float4 a1 = make_float4(0.f, 0.f, 0.f, 0.f);
    #pragma unroll
    for (int t = 0; t < 4; ++t) {
        a0.x += wt[t] * v[t].x;     a0.y += wt[t] * v[t].y;
        a0.z += wt[t] * v[t].z;     a0.w += wt[t] * v[t].w;
        a1.x += wt[4 + t] * v[4 + t].x; a1.y += wt[4 + t] * v[4 + t].y;
        a1.z += wt[4 + t] * v[4 + t].z; a1.w += wt[4 + t] * v[4 + t].w;
    }
    {
        float* sp0 = smem + wslot * 33 + c4 * 4;
        float* sp1 = smem + (wslot + 32) * 33 + c4 * 4;
        sp0[0] = a0.x; sp0[1] = a0.y; sp0[2] = a0.z; sp0[3] = a0.w;
        sp1[0] = a1.x; sp1[1] = a1.y; sp1[2] = a1.z; sp1[3] = a1.w;
    }
    __syncthreads();

    // transpose out of LDS, float4 along w, nontemporal (write-once stream)
    const int c  = tid >> 4;            // 0..15 (x2 passes)
    const int w4 = (tid & 15) * 4;
    #pragma unroll
    for (int p = 0; p < 2; ++p) {
        const int cc = c + p * 16;
        f32x4 o;
        o.x = smem[(w4 + 0) * 33 + cc];
        o.y = smem[(w4 + 1) * 33 + cc];
        o.z = smem[(w4 + 2) * 33 + cc];
        o.w = smem[(w4 + 3) * 33 + cc];
        __builtin_nontemporal_store(
            o, (f32x4*)(out + (((size_t)n * CC + g * GCH + cc) * HH + h) * WW + w4));
    }
}

extern "C" void kernel_launch(void* const* d_in, const int* in_sizes, int n_in,
                              void* d_out, int out_size, void* d_ws, size_t ws_size,
                              hipStream_t stream) {
    const float* in_first = (const float*)d_in[0];
    const float* in_last  = (const float*)d_in[1];
    const float* dw_w     = (const float*)d_in[2];
    const float* dw_b     = (const float*)d_in[3];
    const float* ln_g     = (const float*)d_in[4];
    const float* ln_b     = (const float*)d_in[5];
    const float* off_w    = (const float*)d_in[6];
    const float* off_b    = (const float*)d_in[7];
    float* out = (float*)d_out;

    float* coord_ws = (float*)d_ws;     // 4 MiB

    fused_conv_ln_gelu_off_kernel<<<HH * 2 * NB, 512, 0, stream>>>(
        in_first, dw_w, dw_b, ln_g, ln_b, off_w, off_b, coord_ws);

    sample_kernel<<<HH * NB * GG, 256, 0, stream>>>(in_last, coord_ws, out);
}